// Round 1
// baseline (259.313 us; speedup 1.0000x reference)
//
#include <hip/hip_runtime.h>

#define DIM        512
#define B_POS      1024
#define N_NEG      8192
#define N_RULES    20
#define NEG_RATIO  8

// task index layout for dist_kernel (one wave per task)
#define T_NEG   (B_POS)                 // 1024
#define T_RULE  (B_POS + N_NEG)         // 9216
#define N_TASK  (T_RULE + B_POS * N_RULES)  // 29696

__device__ __forceinline__ float wave_sum(float x) {
#pragma unroll
    for (int off = 32; off > 0; off >>= 1)
        x += __shfl_xor(x, off, 64);
    return x;
}

// ||proj(h) + r - proj(t)|| with w unnormalized:
// d = he - te;  v = d + re - ((d.w)/(w.w)) * w;  return ||v||
__device__ __forceinline__ float transh_dist(
    int h, int r, int t,
    const float* __restrict__ ent, const float* __restrict__ rel,
    const float* __restrict__ nv, int lane)
{
    const float4* wp = (const float4*)(nv  + (size_t)r * DIM);
    const float4* hp = (const float4*)(ent + (size_t)h * DIM);
    const float4* tp = (const float4*)(ent + (size_t)t * DIM);
    const float4* rp = (const float4*)(rel + (size_t)r * DIM);

    float4 wv[2], dv[2], rv[2];
    float ww = 0.f, dw = 0.f;
#pragma unroll
    for (int c = 0; c < 2; ++c) {
        float4 w  = wp[lane + 64 * c];
        float4 hh = hp[lane + 64 * c];
        float4 tt = tp[lane + 64 * c];
        float4 rr = rp[lane + 64 * c];
        float4 d;
        d.x = hh.x - tt.x; d.y = hh.y - tt.y; d.z = hh.z - tt.z; d.w = hh.w - tt.w;
        wv[c] = w; dv[c] = d; rv[c] = rr;
        ww += w.x * w.x + w.y * w.y + w.z * w.z + w.w * w.w;
        dw += d.x * w.x + d.y * w.y + d.z * w.z + d.w * w.w;
    }
    ww = wave_sum(ww);
    dw = wave_sum(dw);
    float s = dw / ww;

    float ss = 0.f;
#pragma unroll
    for (int c = 0; c < 2; ++c) {
        float vx = dv[c].x + rv[c].x - s * wv[c].x;
        float vy = dv[c].y + rv[c].y - s * wv[c].y;
        float vz = dv[c].z + rv[c].z - s * wv[c].z;
        float vw = dv[c].w + rv[c].w - s * wv[c].w;
        ss += vx * vx + vy * vy + vz * vz + vw * vw;
    }
    ss = wave_sum(ss);
    return sqrtf(ss);
}

__global__ __launch_bounds__(256) void dist_kernel(
    const int* __restrict__ pos, const int* __restrict__ neg,
    const int* __restrict__ rule_r1, const int* __restrict__ rule_r2,
    const float* __restrict__ rule_conf,
    const float* __restrict__ ent, const float* __restrict__ rel,
    const float* __restrict__ nv,
    float* __restrict__ dpos, float* __restrict__ dneg,
    float* __restrict__ rule_acc)
{
    int wid  = (int)((blockIdx.x * blockDim.x + threadIdx.x) >> 6);
    int lane = threadIdx.x & 63;
    if (wid >= N_TASK) return;

    if (wid < T_NEG) {                       // pos distances (unique, 1024)
        int i = wid;
        int h = pos[3 * i], r = pos[3 * i + 1], t = pos[3 * i + 2];
        float d = transh_dist(h, r, t, ent, rel, nv, lane);
        if (lane == 0) dpos[i] = d;
    } else if (wid < T_RULE) {               // neg distances (8192)
        int i = wid - T_NEG;
        int h = neg[3 * i], r = neg[3 * i + 1], t = neg[3 * i + 2];
        float d = transh_dist(h, r, t, ent, rel, nv, lane);
        if (lane == 0) dneg[i] = d;
    } else {                                 // rule pairs (1024 x 20, masked)
        int p = wid - T_RULE;
        int i = p / N_RULES;
        int j = p - i * N_RULES;
        if (pos[3 * i + 1] != rule_r1[j]) return;   // mask: ~41/20480 survive
        int h = pos[3 * i], t = pos[3 * i + 2];
        int r2 = rule_r2[j];
        float d = transh_dist(h, r2, t, ent, rel, nv, lane);
        if (lane == 0) atomicAdd(rule_acc, rule_conf[j] * d);
    }
}

__global__ __launch_bounds__(256) void reduce_kernel(
    const float* __restrict__ dpos, const float* __restrict__ dneg,
    const float* __restrict__ rule_acc, float* __restrict__ out)
{
    float s = 0.f;
    for (int k = threadIdx.x; k < N_NEG; k += 256) {
        float v = 1.0f + dpos[k >> 3] - dneg[k];   // repeat-interleave: pos[k/8]
        s += (v > 0.f) ? v : 0.f;
    }
    s = wave_sum(s);
    __shared__ float part[4];
    int w = threadIdx.x >> 6, lane = threadIdx.x & 63;
    if (lane == 0) part[w] = s;
    __syncthreads();
    if (threadIdx.x == 0) {
        float tot = part[0] + part[1] + part[2] + part[3];
        out[0] = tot / (float)N_NEG + 0.5f * rule_acc[0];
    }
}

extern "C" void kernel_launch(void* const* d_in, const int* in_sizes, int n_in,
                              void* d_out, int out_size, void* d_ws, size_t ws_size,
                              hipStream_t stream) {
    const int*   pos       = (const int*)  d_in[0];
    const int*   neg       = (const int*)  d_in[1];
    const int*   rule_r1   = (const int*)  d_in[2];
    const int*   rule_r2   = (const int*)  d_in[3];
    const float* rule_conf = (const float*)d_in[4];
    const float* ent       = (const float*)d_in[5];
    const float* rel       = (const float*)d_in[6];
    const float* nv        = (const float*)d_in[7];
    float* out = (float*)d_out;

    float* rule_acc = (float*)d_ws;          // [0]: rule-loss accumulator
    float* dpos     = rule_acc + 16;         // 1024 floats
    float* dneg     = dpos + B_POS;          // 8192 floats

    hipMemsetAsync(d_ws, 0, 64, stream);     // zero accumulator (ws is poisoned)

    int nblocks = (N_TASK + 3) / 4;          // 4 waves (tasks) per 256-thread block
    dist_kernel<<<nblocks, 256, 0, stream>>>(pos, neg, rule_r1, rule_r2, rule_conf,
                                             ent, rel, nv, dpos, dneg, rule_acc);
    reduce_kernel<<<1, 256, 0, stream>>>(dpos, dneg, rule_acc, out);
}

// Round 2
// 252.825 us; speedup vs baseline: 1.0257x; 1.0257x over previous
//
#include <hip/hip_runtime.h>

#define DIM        512
#define B_POS      1024
#define N_NEG      8192
#define N_RULES    20
#define NEG_RATIO  8
#define NBLK       256   // 4 waves/block, 1024 waves total = 1 per pos triple

__device__ __forceinline__ float wave_sum(float x) {
#pragma unroll
    for (int off = 32; off > 0; off >>= 1)
        x += __shfl_xor(x, off, 64);
    return x;
}

// ||proj(h) + r - proj(t)||, w unnormalized:
// d = he - te;  v = d + re - ((d.w)/(w.w)) * w;  return ||v||
__device__ __forceinline__ float transh_dist(
    int h, int r, int t,
    const float* __restrict__ ent, const float* __restrict__ rel,
    const float* __restrict__ nv, int lane)
{
    const float4* wp = (const float4*)(nv  + (size_t)r * DIM);
    const float4* hp = (const float4*)(ent + (size_t)h * DIM);
    const float4* tp = (const float4*)(ent + (size_t)t * DIM);
    const float4* rp = (const float4*)(rel + (size_t)r * DIM);

    float4 wv[2], dv[2], rv[2];
    float ww = 0.f, dw = 0.f;
#pragma unroll
    for (int c = 0; c < 2; ++c) {
        float4 w  = wp[lane + 64 * c];
        float4 hh = hp[lane + 64 * c];
        float4 tt = tp[lane + 64 * c];
        float4 rr = rp[lane + 64 * c];
        float4 d;
        d.x = hh.x - tt.x; d.y = hh.y - tt.y; d.z = hh.z - tt.z; d.w = hh.w - tt.w;
        wv[c] = w; dv[c] = d; rv[c] = rr;
        ww += w.x * w.x + w.y * w.y + w.z * w.z + w.w * w.w;
        dw += d.x * w.x + d.y * w.y + d.z * w.z + d.w * w.w;
    }
    ww = wave_sum(ww);
    dw = wave_sum(dw);
    float s = dw / ww;

    float ss = 0.f;
#pragma unroll
    for (int c = 0; c < 2; ++c) {
        float vx = dv[c].x + rv[c].x - s * wv[c].x;
        float vy = dv[c].y + rv[c].y - s * wv[c].y;
        float vz = dv[c].z + rv[c].z - s * wv[c].z;
        float vw = dv[c].w + rv[c].w - s * wv[c].w;
        ss += vx * vx + vy * vy + vz * vz + vw * vw;
    }
    ss = wave_sum(ss);
    return sqrtf(ss);
}

// One wave per pos triple: d_pos, its 8 negatives, and the 20-rule loop.
// Per-block LDS reduce -> partial[blockIdx]. No atomics, no zero-init needed.
__global__ __launch_bounds__(256) void fused_kernel(
    const int* __restrict__ pos, const int* __restrict__ neg,
    const int* __restrict__ rule_r1, const int* __restrict__ rule_r2,
    const float* __restrict__ rule_conf,
    const float* __restrict__ ent, const float* __restrict__ rel,
    const float* __restrict__ nv,
    float* __restrict__ partial)
{
    int w    = threadIdx.x >> 6;
    int lane = threadIdx.x & 63;
    int i    = blockIdx.x * 4 + w;          // pos triple index, 0..1023

    int h = pos[3 * i], r = pos[3 * i + 1], t = pos[3 * i + 2];
    float dp = transh_dist(h, r, t, ent, rel, nv, lane);

    // 8 negatives for this pos triple (rows 8i..8i+7, independent h/r/t)
    float relu_sum = 0.f;
#pragma unroll
    for (int k = 0; k < NEG_RATIO; ++k) {
        int n = NEG_RATIO * i + k;
        float dn = transh_dist(neg[3 * n], neg[3 * n + 1], neg[3 * n + 2],
                               ent, rel, nv, lane);
        float v = 1.0f + dp - dn;
        relu_sum += (v > 0.f) ? v : 0.f;
    }

    // rule loss terms: conf_j * dist(h, r2_j, t) where r == r1_j (~41 hits total)
    float rule_acc = 0.f;
    for (int j = 0; j < N_RULES; ++j) {
        if (r == rule_r1[j]) {
            float d = transh_dist(h, rule_r2[j], t, ent, rel, nv, lane);
            rule_acc += rule_conf[j] * d;
        }
    }

    float contrib = relu_sum * (1.0f / (float)N_NEG) + 0.5f * rule_acc;

    __shared__ float part[4];
    if (lane == 0) part[w] = contrib;
    __syncthreads();
    if (threadIdx.x == 0)
        partial[blockIdx.x] = part[0] + part[1] + part[2] + part[3];
}

__global__ __launch_bounds__(64) void final_reduce(
    const float* __restrict__ partial, float* __restrict__ out)
{
    int lane = threadIdx.x;
    float s = 0.f;
#pragma unroll
    for (int m = 0; m < NBLK / 64; ++m)
        s += partial[lane + 64 * m];
    s = wave_sum(s);
    if (lane == 0) out[0] = s;
}

extern "C" void kernel_launch(void* const* d_in, const int* in_sizes, int n_in,
                              void* d_out, int out_size, void* d_ws, size_t ws_size,
                              hipStream_t stream) {
    const int*   pos       = (const int*)  d_in[0];
    const int*   neg       = (const int*)  d_in[1];
    const int*   rule_r1   = (const int*)  d_in[2];
    const int*   rule_r2   = (const int*)  d_in[3];
    const float* rule_conf = (const float*)d_in[4];
    const float* ent       = (const float*)d_in[5];
    const float* rel       = (const float*)d_in[6];
    const float* nv        = (const float*)d_in[7];
    float* out     = (float*)d_out;
    float* partial = (float*)d_ws;   // NBLK floats, every block writes -> no init

    fused_kernel<<<NBLK, 256, 0, stream>>>(pos, neg, rule_r1, rule_r2, rule_conf,
                                           ent, rel, nv, partial);
    final_reduce<<<1, 64, 0, stream>>>(partial, out);
}